// Round 16
// baseline (815.252 us; speedup 1.0000x reference)
//
#include <hip/hip_runtime.h>

#define NUSERS 100000
#define NITEMS 200000
#define NNODES 300000
#define DIM 64
#define NEDGES 9600000

#define K1 1024                    // buckets
#define ROWS1 293                  // ceil(300000/1024); K1*ROWS1 = 300032
#define CAP1 10240                 // slots/bucket (mean 9375, +8.9 sigma)
#define SLOTS 16                   // LDS staging slots per bucket
#define GCS 16                     // gcurs stride in ints (64B padded)
#define PTHREADS 1024
#define PNBLK 256
#define EPBLK (NEDGES / PNBLK)     // 37500
#define ROUND (PTHREADS * 4)       // 4096 edges per round
#define REG_E1 20                  // ceil(CAP1/512)

static_assert(K1 * ROWS1 >= NNODES, "bucket coverage");
static_assert(NNODES <= (1 << 19), "col fits 19 bits");
static_assert(ROWS1 <= (1 << 13), "lrow fits 13 bits");
static_assert(REG_E1 * 512 >= CAP1, "reg staging covers bucket");
static_assert(EPBLK * PNBLK == NEDGES, "exact partition coverage");
static_assert(EPBLK % 4 == 0, "int4 alignment");

typedef float fx2 __attribute__((ext_vector_type(2)));
typedef float fx4 __attribute__((ext_vector_type(4)));   // clang vector: nt-store OK

__device__ __forceinline__ unsigned short f2bf(float f) {
    unsigned u = __float_as_uint(f);
    u += 0x7FFFu + ((u >> 16) & 1u);         // RNE
    return (unsigned short)(u >> 16);
}
__device__ __forceinline__ float bf2f(unsigned short h) {
    return __uint_as_float((unsigned)h << 16);
}

// pack 4 f32 -> 4 x fp8 e4m3 (one dword), HW RNE+sat
__device__ __forceinline__ unsigned pack_fp8x4(float a, float b, float c, float d) {
    int p = __builtin_amdgcn_cvt_pk_fp8_f32(a, b, 0, false);   // word 0
    p = __builtin_amdgcn_cvt_pk_fp8_f32(c, d, p, true);        // word 1
    return (unsigned)p;
}

__device__ __forceinline__ void acc_fp8(float4& acc, unsigned g, float f) {
    fx2 lo = __builtin_amdgcn_cvt_pk_f32_fp8((int)g, false);
    fx2 hi = __builtin_amdgcn_cvt_pk_f32_fp8((int)g, true);
    acc.x += f * lo.x; acc.y += f * lo.y;
    acc.z += f * hi.x; acc.w += f * hi.y;
}

__device__ __forceinline__ void nt_store4(float4 v, float4* p) {
    fx4 w = {v.x, v.y, v.z, v.w};
    __builtin_nontemporal_store(w, (fx4*)p);
}

// ---------------------------------------------------------------------------
// concat: e0 = [user;item] f32 (nt store), fp8 table t0 = fp8(16*e0);
// also zeroes the cursor array (fused former zero_kernel)
// ---------------------------------------------------------------------------
__global__ void concat_kernel(const float4* __restrict__ u,
                              const float4* __restrict__ it,
                              float4* __restrict__ e0,
                              unsigned* __restrict__ t0,
                              int* __restrict__ gcurs) {
    int i = blockIdx.x * blockDim.x + threadIdx.x;
    if (i < K1 * GCS) gcurs[i] = 0;
    const int nu4 = NUSERS * 16, tot4 = NNODES * 16;
    if (i >= tot4) return;
    float4 v = (i < nu4) ? u[i] : it[i - nu4];
    nt_store4(v, &e0[i]);
    t0[i] = pack_fp8x4(v.x * 16.f, v.y * 16.f, v.z * 16.f, v.w * 16.f);
}

// ---------------------------------------------------------------------------
// partition with LDS chunk staging: every global payload store is a
// wave-coalesced 16-entry chunk; one global atomic per chunk (not per edge).
// ---------------------------------------------------------------------------
__global__ __launch_bounds__(1024) void part_kernel(const int* __restrict__ row,
                                                    const int* __restrict__ col,
                                                    const float* __restrict__ val,
                                                    int* __restrict__ gcurs,
                                                    unsigned* __restrict__ keys,
                                                    unsigned short* __restrict__ vals) {
    __shared__ unsigned skey[K1][SLOTS];      // 64 KB
    __shared__ unsigned short sval[K1][SLOTS];// 32 KB
    __shared__ int scnt[K1];                  //  4 KB
    __shared__ int descb[K1], descg[K1], descn[K1];  // 12 KB
    __shared__ int ndesc;
    const int t = threadIdx.x;
    for (int j = t; j < K1; j += PTHREADS) scnt[j] = 0;
    __syncthreads();

    const int base = blockIdx.x * EPBLK;
    const int bend = base + EPBLK;

    for (int rb = base; rb < bend; rb += ROUND) {
        int e0 = rb + t * 4;
        unsigned needmask = 0;
        int bk[4]; unsigned kk[4]; unsigned short vv[4];
        if (e0 + 3 < bend) {
            int4   rr = *(const int4*)(row + e0);
            int4   cc = *(const int4*)(col + e0);
            float4 ff = *(const float4*)(val + e0);
            bk[0] = rr.x / ROWS1; bk[1] = rr.y / ROWS1;
            bk[2] = rr.z / ROWS1; bk[3] = rr.w / ROWS1;
            kk[0] = ((unsigned)(rr.x - bk[0] * ROWS1) << 19) | (unsigned)cc.x;
            kk[1] = ((unsigned)(rr.y - bk[1] * ROWS1) << 19) | (unsigned)cc.y;
            kk[2] = ((unsigned)(rr.z - bk[2] * ROWS1) << 19) | (unsigned)cc.z;
            kk[3] = ((unsigned)(rr.w - bk[3] * ROWS1) << 19) | (unsigned)cc.w;
            vv[0] = f2bf(ff.x); vv[1] = f2bf(ff.y);
            vv[2] = f2bf(ff.z); vv[3] = f2bf(ff.w);
            needmask = 0xF;
        } else if (e0 < bend) {
            int n = bend - e0;
            for (int j = 0; j < n; ++j) {
                int r = row[e0 + j];
                int b = r / ROWS1;
                bk[j] = b;
                kk[j] = ((unsigned)(r - b * ROWS1) << 19) | (unsigned)col[e0 + j];
                vv[j] = f2bf(val[e0 + j]);
                needmask |= (1u << j);
            }
        }
        while (true) {
            if (needmask) {
#pragma unroll
                for (int j = 0; j < 4; ++j) {
                    if (needmask & (1u << j)) {
                        int pos = atomicAdd(&scnt[bk[j]], 1);
                        if (pos < SLOTS) {
                            skey[bk[j]][pos] = kk[j];
                            sval[bk[j]][pos] = vv[j];
                            needmask &= ~(1u << j);
                        }
                    }
                }
            }
            __syncthreads();
            if (t == 0) ndesc = 0;
            __syncthreads();
            {   // identify full buckets, reserve global chunks
                int c = scnt[t];                     // PTHREADS == K1
                if (c >= SLOTS) {
                    int gb = atomicAdd(&gcurs[t * GCS], SLOTS);
                    int d = atomicAdd(&ndesc, 1);
                    descb[d] = t; descg[d] = gb; descn[d] = SLOTS;
                    scnt[t] = 0;
                }
            }
            __syncthreads();
            int nd = ndesc;
            // flat-indexed coalesced chunk copy
            for (int i = t; i < nd * SLOTS; i += PTHREADS) {
                int d = i >> 4, sl = i & (SLOTS - 1);
                int b2 = descb[d];
                int go = descg[d] + sl;
                if (go < CAP1) {
                    size_t o = (size_t)b2 * CAP1 + go;
                    keys[o] = skey[b2][sl];
                    vals[o] = sval[b2][sl];
                }
            }
            int more = __syncthreads_or(needmask != 0);
            if (!more) break;
        }
    }

    // final partial flush (still wave-coalesced per chunk)
    if (t == 0) ndesc = 0;
    __syncthreads();
    {
        int c = scnt[t];
        if (c > 0) {
            if (c > SLOTS) c = SLOTS;
            int gb = atomicAdd(&gcurs[t * GCS], c);
            int d = atomicAdd(&ndesc, 1);
            descb[d] = t; descg[d] = gb; descn[d] = c;
        }
    }
    __syncthreads();
    int nd = ndesc;
    for (int i = t; i < nd * SLOTS; i += PTHREADS) {
        int d = i >> 4, sl = i & (SLOTS - 1);
        if (sl < descn[d]) {
            int b2 = descb[d];
            int go = descg[d] + sl;
            if (go < CAP1) {
                size_t o = (size_t)b2 * CAP1 + go;
                keys[o] = skey[b2][sl];
                vals[o] = sval[b2][sl];
            }
        }
    }
}

// ---------------------------------------------------------------------------
// per-bucket sort into row order; emits per-row start offsets
// ---------------------------------------------------------------------------
__global__ __launch_bounds__(512) void bsort_kernel(const int* __restrict__ gcurs,
                                                    unsigned* __restrict__ keys,
                                                    unsigned short* __restrict__ vals,
                                                    int* __restrict__ rstart) {
    __shared__ unsigned skey[CAP1];           // 40960 B
    __shared__ unsigned short sval[CAP1];     // 20480 B
    __shared__ int shist[ROWS1];
    __shared__ int sscan[512];
    __shared__ int scur[ROWS1];
    const int b = blockIdx.x;
    const int base = b * ROWS1;
    const int t = threadIdx.x;
    if (t < ROWS1) shist[t] = 0;
    __syncthreads();
    int cnt = gcurs[b * GCS];
    if (cnt > CAP1) cnt = CAP1;
    size_t bb = (size_t)b * CAP1;
    for (int idx = t; idx < cnt; idx += 512) {
        unsigned k = keys[bb + idx];
        skey[idx] = k;
        sval[idx] = vals[bb + idx];
        atomicAdd(&shist[k >> 19], 1);
    }
    __syncthreads();

    // in-block exclusive scan of the ROWS1 row counts
    sscan[t] = (t < ROWS1) ? shist[t] : 0;
    __syncthreads();
    for (int off = 1; off < 512; off <<= 1) {
        int tmp = (t >= off) ? sscan[t - off] : 0;
        __syncthreads();
        sscan[t] += tmp;
        __syncthreads();
    }
    if (t < ROWS1) {
        int excl = sscan[t] - shist[t];
        scur[t] = excl;
        int gr = base + t;
        if (gr < NNODES) rstart[gr] = excl;
    }

    // LDS -> regs (no RAW hazard for the in-place scatter)
    unsigned rk[REG_E1];
    unsigned short rv[REG_E1];
#pragma unroll
    for (int k = 0; k < REG_E1; ++k) {
        int j = t + k * 512;
        if (j < cnt) { rk[k] = skey[j]; rv[k] = sval[j]; }
    }
    __syncthreads();
#pragma unroll
    for (int k = 0; k < REG_E1; ++k) {
        int j = t + k * 512;
        if (j < cnt) {
            int lr = rk[k] >> 19;
            int lpos = atomicAdd(&scur[lr], 1);
            skey[lpos] = rk[k];
            sval[lpos] = rv[k];
        }
    }
    __syncthreads();

    // coalesced writeback (sorted layout)
    for (int j = t; j < cnt; j += 512) {
        keys[bb + j] = skey[j];
        vals[bb + j] = sval[j];
    }
}

// ---------------------------------------------------------------------------
// SpMM: 4 rows/wave (16 lanes x 4B fp8x4 = 64 dims), fp8 gathers (1 line/row),
// f32 accum. CSR metadata via nontemporal loads (no reuse within a layer);
// y via nontemporal stores (keeps L2 for the fp8 gather table).
// Scale ladder: layer1 OSH=4, layer2 OSH=8, layer3 OSH=12 (tables hold 16^L*x).
// ---------------------------------------------------------------------------
template <bool WRITE_T, int OSH>
__global__ __launch_bounds__(256) void spmm_kernel(const int* __restrict__ rstart,
                                                   const int* __restrict__ gcurs,
                                                   const unsigned* __restrict__ keys,
                                                   const unsigned short* __restrict__ vals,
                                                   const unsigned* __restrict__ xt,
                                                   float4* __restrict__ y,
                                                   unsigned* __restrict__ tn) {
    constexpr float OUT_SCALE = 1.0f / (float)(1 << OSH);
    int tid = blockIdx.x * 256 + threadIdx.x;
    int r = tid >> 4;
    int q = tid & 15;
    if (r >= NNODES) return;
    int bkt = r / ROWS1;
    int lr  = r - bkt * ROWS1;
    int s = rstart[r];
    int e_;
    if (lr == ROWS1 - 1 || r == NNODES - 1) {
        e_ = gcurs[bkt * GCS];
        if (e_ > CAP1) e_ = CAP1;
    } else {
        e_ = rstart[r + 1];
    }
    int n = e_ - s;
    size_t i = (size_t)bkt * CAP1 + s;
    float4 acc = {0.f, 0.f, 0.f, 0.f};
    for (; n >= 8; n -= 8, i += 8) {
        unsigned k[8]; unsigned short vv[8]; unsigned g[8];
#pragma unroll
        for (int j = 0; j < 8; ++j) {
            k[j]  = __builtin_nontemporal_load(&keys[i + j]);
            vv[j] = __builtin_nontemporal_load(&vals[i + j]);
        }
#pragma unroll
        for (int j = 0; j < 8; ++j) g[j] = xt[(size_t)(k[j] & 0x7FFFF) * 16 + q];
#pragma unroll
        for (int j = 0; j < 8; ++j) acc_fp8(acc, g[j], bf2f(vv[j]));
    }
    for (; n > 0; --n, ++i) {
        unsigned kk = __builtin_nontemporal_load(&keys[i]);
        unsigned short vs = __builtin_nontemporal_load(&vals[i]);
        unsigned g = xt[(size_t)(kk & 0x7FFFF) * 16 + q];
        acc_fp8(acc, g, bf2f(vs));
    }
    float4 yv;
    yv.x = acc.x * OUT_SCALE; yv.y = acc.y * OUT_SCALE;
    yv.z = acc.z * OUT_SCALE; yv.w = acc.w * OUT_SCALE;
    nt_store4(yv, &y[(size_t)r * 16 + q]);
    if (WRITE_T) {
        tn[(size_t)r * 16 + q] =
            pack_fp8x4(acc.x * 16.f, acc.y * 16.f, acc.z * 16.f, acc.w * 16.f);
    }
}

// ---------------------------------------------------------------------------
// fallback atomic SpMM (only if ws too small)
// ---------------------------------------------------------------------------
__global__ void spmm_atomic_kernel(const int* __restrict__ row,
                                   const int* __restrict__ col,
                                   const float* __restrict__ val,
                                   const float* __restrict__ x,
                                   float* __restrict__ y) {
    long long tid = (long long)blockIdx.x * blockDim.x + threadIdx.x;
    if (tid >= (long long)NEDGES * 16) return;
    int e = (int)(tid >> 4);
    int q = (int)(tid & 15);
    int r = row[e], c = col[e];
    float v = val[e];
    float4 xv = ((const float4*)x)[(size_t)c * 16 + q];
    float* yp = y + (size_t)r * 64 + q * 4;
    atomicAdd(yp + 0, v * xv.x);
    atomicAdd(yp + 1, v * xv.y);
    atomicAdd(yp + 2, v * xv.z);
    atomicAdd(yp + 3, v * xv.w);
}

// ---------------------------------------------------------------------------
// finalize: mean over 4 embeddings, split users/items (overwrites tables)
// ---------------------------------------------------------------------------
__global__ void finalize_kernel(const float4* __restrict__ e0,
                                const float4* __restrict__ e1,
                                const float4* __restrict__ e2,
                                const float4* __restrict__ e3,
                                float4* __restrict__ users,
                                float4* __restrict__ items) {
    int i = blockIdx.x * blockDim.x + threadIdx.x;
    const int tot4 = NNODES * 16;
    if (i >= tot4) return;
    float4 a = e0[i], b = e1[i], c = e2[i], d = e3[i];
    float4 m;
    m.x = (a.x + b.x + c.x + d.x) * 0.25f;
    m.y = (a.y + b.y + c.y + d.y) * 0.25f;
    m.z = (a.z + b.z + c.z + d.z) * 0.25f;
    m.w = (a.w + b.w + c.w + d.w) * 0.25f;
    const int nu4 = NUSERS * 16;
    if (i < nu4) users[i] = m;
    else         items[i - nu4] = m;
}

extern "C" void kernel_launch(void* const* d_in, const int* in_sizes, int n_in,
                              void* d_out, int out_size, void* d_ws, size_t ws_size,
                              hipStream_t stream) {
    const float* user_emb = (const float*)d_in[0];
    const float* item_emb = (const float*)d_in[1];
    const int*   adj_row  = (const int*)d_in[2];
    const int*   adj_col  = (const int*)d_in[3];
    const float* adj_val  = (const float*)d_in[4];

    float* out   = (float*)d_out;
    float* users = out;
    float* items = out + (size_t)NUSERS * DIM;
    float* e0    = out + (size_t)NNODES * DIM;
    float* e1    = e0 + (size_t)NNODES * DIM;
    float* e2    = e1 + (size_t)NNODES * DIM;
    float* e3    = e2 + (size_t)NNODES * DIM;

    // fp8 gather tables (19.2 MB each) ping-pong inside the users+items
    // region (76.8 MB); finalize overwrites them at the end.
    unsigned* tA = (unsigned*)out;                       // t0, t2
    unsigned* tB = tA + (size_t)NNODES * 16;             // t1

    const int tot4  = NNODES * 16;
    const int cblk  = 256;
    const int cgrid = (tot4 + cblk - 1) / cblk;

    // workspace (~66 MB)
    char* ws = (char*)d_ws;
    size_t off = 0;
    auto alloc = [&](size_t bytes) {
        char* p = ws + off;
        off += (bytes + 255) & ~(size_t)255;
        return p;
    };
    int*            gcurs  = (int*)            alloc((size_t)K1 * GCS * sizeof(int));
    int*            rstart = (int*)            alloc((size_t)NNODES * sizeof(int));
    unsigned*       keys   = (unsigned*)       alloc((size_t)K1 * CAP1 * sizeof(unsigned));
    unsigned short* vals   = (unsigned short*) alloc((size_t)K1 * CAP1 * sizeof(unsigned short));
    bool have_ws = (off <= ws_size);

    concat_kernel<<<cgrid, cblk, 0, stream>>>(
        (const float4*)user_emb, (const float4*)item_emb, (float4*)e0, tA, gcurs);

    if (have_ws) {
        part_kernel<<<PNBLK, PTHREADS, 0, stream>>>(adj_row, adj_col, adj_val,
                                                    gcurs, keys, vals);
        bsort_kernel<<<K1, 512, 0, stream>>>(gcurs, keys, vals, rstart);

        const int sgrid = (NNODES * 16 + 255) / 256;   // 18750
        spmm_kernel<true,  4><<<sgrid, 256, 0, stream>>>(rstart, gcurs, keys, vals,
                                                         tA, (float4*)e1, tB);
        spmm_kernel<true,  8><<<sgrid, 256, 0, stream>>>(rstart, gcurs, keys, vals,
                                                         tB, (float4*)e2, tA);
        spmm_kernel<false, 12><<<sgrid, 256, 0, stream>>>(rstart, gcurs, keys, vals,
                                                          tA, (float4*)e3, nullptr);
    } else {
        hipMemsetAsync(e1, 0, (size_t)3 * NNODES * DIM * sizeof(float), stream);
        const long long st = (long long)NEDGES * 16;
        const int sgrid = (int)((st + 255) / 256);
        spmm_atomic_kernel<<<sgrid, 256, 0, stream>>>(adj_row, adj_col, adj_val, e0, e1);
        spmm_atomic_kernel<<<sgrid, 256, 0, stream>>>(adj_row, adj_col, adj_val, e1, e2);
        spmm_atomic_kernel<<<sgrid, 256, 0, stream>>>(adj_row, adj_col, adj_val, e2, e3);
    }

    finalize_kernel<<<cgrid, cblk, 0, stream>>>(
        (const float4*)e0, (const float4*)e1, (const float4*)e2, (const float4*)e3,
        (float4*)users, (float4*)items);
}

// Round 17
// 692.700 us; speedup vs baseline: 1.1769x; 1.1769x over previous
//
#include <hip/hip_runtime.h>

#define NUSERS 100000
#define NITEMS 200000
#define NNODES 300000
#define DIM 64
#define NEDGES 9600000

#define K1 1024                    // buckets
#define ROWS1 293                  // ceil(300000/1024); K1*ROWS1 = 300032
#define CAP1 10240                 // slots/bucket (mean 9375, +8.9 sigma)
#define SLOTS 16                   // LDS staging slots per bucket
#define GCS 16                     // gcurs stride in ints (64B padded)
#define PTHREADS 1024
#define PNBLK 256
#define EPBLK (NEDGES / PNBLK)     // 37500
#define ROUND (PTHREADS * 4)       // 4096 edges per round
#define REG_E1 20                  // ceil(CAP1/512)

static_assert(K1 * ROWS1 >= NNODES, "bucket coverage");
static_assert(NNODES <= (1 << 19), "col fits 19 bits");
static_assert(ROWS1 <= (1 << 13), "lrow fits 13 bits");
static_assert(REG_E1 * 512 >= CAP1, "reg staging covers bucket");
static_assert(EPBLK * PNBLK == NEDGES, "exact partition coverage");
static_assert(EPBLK % 4 == 0, "int4 alignment");

typedef float fx2 __attribute__((ext_vector_type(2)));

__device__ __forceinline__ unsigned short f2bf(float f) {
    unsigned u = __float_as_uint(f);
    u += 0x7FFFu + ((u >> 16) & 1u);         // RNE
    return (unsigned short)(u >> 16);
}
__device__ __forceinline__ float bf2f(unsigned short h) {
    return __uint_as_float((unsigned)h << 16);
}

// pack 4 f32 -> 4 x fp8 e4m3 (one dword), HW RNE+sat
__device__ __forceinline__ unsigned pack_fp8x4(float a, float b, float c, float d) {
    int p = __builtin_amdgcn_cvt_pk_fp8_f32(a, b, 0, false);   // word 0
    p = __builtin_amdgcn_cvt_pk_fp8_f32(c, d, p, true);        // word 1
    return (unsigned)p;
}

__device__ __forceinline__ void acc_fp8(float4& acc, unsigned g, float f) {
    fx2 lo = __builtin_amdgcn_cvt_pk_f32_fp8((int)g, false);
    fx2 hi = __builtin_amdgcn_cvt_pk_f32_fp8((int)g, true);
    acc.x += f * lo.x; acc.y += f * lo.y;
    acc.z += f * hi.x; acc.w += f * hi.y;
}

// ---------------------------------------------------------------------------
// concat: e0 = [user;item] f32, plus fp8 gather table t0 = fp8(16*e0)
// ---------------------------------------------------------------------------
__global__ void concat_kernel(const float4* __restrict__ u,
                              const float4* __restrict__ it,
                              float4* __restrict__ e0,
                              unsigned* __restrict__ t0) {
    int i = blockIdx.x * blockDim.x + threadIdx.x;
    const int nu4 = NUSERS * 16, tot4 = NNODES * 16;
    if (i >= tot4) return;
    float4 v = (i < nu4) ? u[i] : it[i - nu4];
    e0[i] = v;
    t0[i] = pack_fp8x4(v.x * 16.f, v.y * 16.f, v.z * 16.f, v.w * 16.f);
}

// zero the (tiny) cursor array without a rocclr fill dispatch
__global__ void zero_kernel(int* __restrict__ p, int n) {
    int i = blockIdx.x * blockDim.x + threadIdx.x;
    if (i < n) p[i] = 0;
}

// ---------------------------------------------------------------------------
// partition with LDS chunk staging: every global payload store is a
// wave-coalesced 16-entry chunk; one global atomic per chunk (not per edge).
// ---------------------------------------------------------------------------
__global__ __launch_bounds__(1024) void part_kernel(const int* __restrict__ row,
                                                    const int* __restrict__ col,
                                                    const float* __restrict__ val,
                                                    int* __restrict__ gcurs,
                                                    unsigned* __restrict__ keys,
                                                    unsigned short* __restrict__ vals) {
    __shared__ unsigned skey[K1][SLOTS];      // 64 KB
    __shared__ unsigned short sval[K1][SLOTS];// 32 KB
    __shared__ int scnt[K1];                  //  4 KB
    __shared__ int descb[K1], descg[K1], descn[K1];  // 12 KB
    __shared__ int ndesc;
    const int t = threadIdx.x;
    for (int j = t; j < K1; j += PTHREADS) scnt[j] = 0;
    __syncthreads();

    const int base = blockIdx.x * EPBLK;
    const int bend = base + EPBLK;

    for (int rb = base; rb < bend; rb += ROUND) {
        int e0 = rb + t * 4;
        unsigned needmask = 0;
        int bk[4]; unsigned kk[4]; unsigned short vv[4];
        if (e0 + 3 < bend) {
            int4   rr = *(const int4*)(row + e0);
            int4   cc = *(const int4*)(col + e0);
            float4 ff = *(const float4*)(val + e0);
            bk[0] = rr.x / ROWS1; bk[1] = rr.y / ROWS1;
            bk[2] = rr.z / ROWS1; bk[3] = rr.w / ROWS1;
            kk[0] = ((unsigned)(rr.x - bk[0] * ROWS1) << 19) | (unsigned)cc.x;
            kk[1] = ((unsigned)(rr.y - bk[1] * ROWS1) << 19) | (unsigned)cc.y;
            kk[2] = ((unsigned)(rr.z - bk[2] * ROWS1) << 19) | (unsigned)cc.z;
            kk[3] = ((unsigned)(rr.w - bk[3] * ROWS1) << 19) | (unsigned)cc.w;
            vv[0] = f2bf(ff.x); vv[1] = f2bf(ff.y);
            vv[2] = f2bf(ff.z); vv[3] = f2bf(ff.w);
            needmask = 0xF;
        } else if (e0 < bend) {
            int n = bend - e0;
            for (int j = 0; j < n; ++j) {
                int r = row[e0 + j];
                int b = r / ROWS1;
                bk[j] = b;
                kk[j] = ((unsigned)(r - b * ROWS1) << 19) | (unsigned)col[e0 + j];
                vv[j] = f2bf(val[e0 + j]);
                needmask |= (1u << j);
            }
        }
        while (true) {
            if (needmask) {
#pragma unroll
                for (int j = 0; j < 4; ++j) {
                    if (needmask & (1u << j)) {
                        int pos = atomicAdd(&scnt[bk[j]], 1);
                        if (pos < SLOTS) {
                            skey[bk[j]][pos] = kk[j];
                            sval[bk[j]][pos] = vv[j];
                            needmask &= ~(1u << j);
                        }
                    }
                }
            }
            __syncthreads();
            if (t == 0) ndesc = 0;
            __syncthreads();
            {   // identify full buckets, reserve global chunks
                int c = scnt[t];                     // PTHREADS == K1
                if (c >= SLOTS) {
                    int gb = atomicAdd(&gcurs[t * GCS], SLOTS);
                    int d = atomicAdd(&ndesc, 1);
                    descb[d] = t; descg[d] = gb; descn[d] = SLOTS;
                    scnt[t] = 0;
                }
            }
            __syncthreads();
            int nd = ndesc;
            // flat-indexed coalesced chunk copy
            for (int i = t; i < nd * SLOTS; i += PTHREADS) {
                int d = i >> 4, sl = i & (SLOTS - 1);
                int b2 = descb[d];
                int go = descg[d] + sl;
                if (go < CAP1) {
                    size_t o = (size_t)b2 * CAP1 + go;
                    keys[o] = skey[b2][sl];
                    vals[o] = sval[b2][sl];
                }
            }
            int more = __syncthreads_or(needmask != 0);
            if (!more) break;
        }
    }

    // final partial flush (still wave-coalesced per chunk)
    if (t == 0) ndesc = 0;
    __syncthreads();
    {
        int c = scnt[t];
        if (c > 0) {
            if (c > SLOTS) c = SLOTS;
            int gb = atomicAdd(&gcurs[t * GCS], c);
            int d = atomicAdd(&ndesc, 1);
            descb[d] = t; descg[d] = gb; descn[d] = c;
        }
    }
    __syncthreads();
    int nd = ndesc;
    for (int i = t; i < nd * SLOTS; i += PTHREADS) {
        int d = i >> 4, sl = i & (SLOTS - 1);
        if (sl < descn[d]) {
            int b2 = descb[d];
            int go = descg[d] + sl;
            if (go < CAP1) {
                size_t o = (size_t)b2 * CAP1 + go;
                keys[o] = skey[b2][sl];
                vals[o] = sval[b2][sl];
            }
        }
    }
}

// ---------------------------------------------------------------------------
// per-bucket sort into row order; emits per-row start offsets
// ---------------------------------------------------------------------------
__global__ __launch_bounds__(512) void bsort_kernel(const int* __restrict__ gcurs,
                                                    unsigned* __restrict__ keys,
                                                    unsigned short* __restrict__ vals,
                                                    int* __restrict__ rstart) {
    __shared__ unsigned skey[CAP1];           // 40960 B
    __shared__ unsigned short sval[CAP1];     // 20480 B
    __shared__ int shist[ROWS1];
    __shared__ int sscan[512];
    __shared__ int scur[ROWS1];
    const int b = blockIdx.x;
    const int base = b * ROWS1;
    const int t = threadIdx.x;
    if (t < ROWS1) shist[t] = 0;
    __syncthreads();
    int cnt = gcurs[b * GCS];
    if (cnt > CAP1) cnt = CAP1;
    size_t bb = (size_t)b * CAP1;
    for (int idx = t; idx < cnt; idx += 512) {
        unsigned k = keys[bb + idx];
        skey[idx] = k;
        sval[idx] = vals[bb + idx];
        atomicAdd(&shist[k >> 19], 1);
    }
    __syncthreads();

    // in-block exclusive scan of the ROWS1 row counts
    sscan[t] = (t < ROWS1) ? shist[t] : 0;
    __syncthreads();
    for (int off = 1; off < 512; off <<= 1) {
        int tmp = (t >= off) ? sscan[t - off] : 0;
        __syncthreads();
        sscan[t] += tmp;
        __syncthreads();
    }
    if (t < ROWS1) {
        int excl = sscan[t] - shist[t];
        scur[t] = excl;
        int gr = base + t;
        if (gr < NNODES) rstart[gr] = excl;
    }

    // LDS -> regs (no RAW hazard for the in-place scatter)
    unsigned rk[REG_E1];
    unsigned short rv[REG_E1];
#pragma unroll
    for (int k = 0; k < REG_E1; ++k) {
        int j = t + k * 512;
        if (j < cnt) { rk[k] = skey[j]; rv[k] = sval[j]; }
    }
    __syncthreads();
#pragma unroll
    for (int k = 0; k < REG_E1; ++k) {
        int j = t + k * 512;
        if (j < cnt) {
            int lr = rk[k] >> 19;
            int lpos = atomicAdd(&scur[lr], 1);
            skey[lpos] = rk[k];
            sval[lpos] = rv[k];
        }
    }
    __syncthreads();

    // coalesced writeback (sorted layout)
    for (int j = t; j < cnt; j += 512) {
        keys[bb + j] = skey[j];
        vals[bb + j] = sval[j];
    }
}

// ---------------------------------------------------------------------------
// SpMM: 4 rows/wave (16 lanes x 4B fp8x4 = 64 dims), fp8 gathers (1 line/row),
// f32 accum. Scale ladder: layer1 OSH=4, layer2 OSH=8, layer3 OSH=12
// (tables hold 16^L * x).
// ---------------------------------------------------------------------------
template <bool WRITE_T, int OSH>
__global__ __launch_bounds__(256) void spmm_kernel(const int* __restrict__ rstart,
                                                   const int* __restrict__ gcurs,
                                                   const unsigned* __restrict__ keys,
                                                   const unsigned short* __restrict__ vals,
                                                   const unsigned* __restrict__ xt,
                                                   float4* __restrict__ y,
                                                   unsigned* __restrict__ tn) {
    constexpr float OUT_SCALE = 1.0f / (float)(1 << OSH);
    int tid = blockIdx.x * 256 + threadIdx.x;
    int r = tid >> 4;
    int q = tid & 15;
    if (r >= NNODES) return;
    int bkt = r / ROWS1;
    int lr  = r - bkt * ROWS1;
    int s = rstart[r];
    int e_;
    if (lr == ROWS1 - 1 || r == NNODES - 1) {
        e_ = gcurs[bkt * GCS];
        if (e_ > CAP1) e_ = CAP1;
    } else {
        e_ = rstart[r + 1];
    }
    int n = e_ - s;
    size_t i = (size_t)bkt * CAP1 + s;
    float4 acc = {0.f, 0.f, 0.f, 0.f};
    for (; n >= 8; n -= 8, i += 8) {
        unsigned k[8]; unsigned short vv[8]; unsigned g[8];
#pragma unroll
        for (int j = 0; j < 8; ++j) { k[j] = keys[i + j]; vv[j] = vals[i + j]; }
#pragma unroll
        for (int j = 0; j < 8; ++j) g[j] = xt[(size_t)(k[j] & 0x7FFFF) * 16 + q];
#pragma unroll
        for (int j = 0; j < 8; ++j) acc_fp8(acc, g[j], bf2f(vv[j]));
    }
    for (; n > 0; --n, ++i) {
        unsigned g = xt[(size_t)(keys[i] & 0x7FFFF) * 16 + q];
        acc_fp8(acc, g, bf2f(vals[i]));
    }
    float4 yv;
    yv.x = acc.x * OUT_SCALE; yv.y = acc.y * OUT_SCALE;
    yv.z = acc.z * OUT_SCALE; yv.w = acc.w * OUT_SCALE;
    y[(size_t)r * 16 + q] = yv;
    if (WRITE_T) {
        tn[(size_t)r * 16 + q] =
            pack_fp8x4(acc.x * 16.f, acc.y * 16.f, acc.z * 16.f, acc.w * 16.f);
    }
}

// ---------------------------------------------------------------------------
// fallback atomic SpMM (only if ws too small)
// ---------------------------------------------------------------------------
__global__ void spmm_atomic_kernel(const int* __restrict__ row,
                                   const int* __restrict__ col,
                                   const float* __restrict__ val,
                                   const float* __restrict__ x,
                                   float* __restrict__ y) {
    long long tid = (long long)blockIdx.x * blockDim.x + threadIdx.x;
    if (tid >= (long long)NEDGES * 16) return;
    int e = (int)(tid >> 4);
    int q = (int)(tid & 15);
    int r = row[e], c = col[e];
    float v = val[e];
    float4 xv = ((const float4*)x)[(size_t)c * 16 + q];
    float* yp = y + (size_t)r * 64 + q * 4;
    atomicAdd(yp + 0, v * xv.x);
    atomicAdd(yp + 1, v * xv.y);
    atomicAdd(yp + 2, v * xv.z);
    atomicAdd(yp + 3, v * xv.w);
}

// ---------------------------------------------------------------------------
// finalize: mean over 4 embeddings, split users/items (overwrites tables)
// ---------------------------------------------------------------------------
__global__ void finalize_kernel(const float4* __restrict__ e0,
                                const float4* __restrict__ e1,
                                const float4* __restrict__ e2,
                                const float4* __restrict__ e3,
                                float4* __restrict__ users,
                                float4* __restrict__ items) {
    int i = blockIdx.x * blockDim.x + threadIdx.x;
    const int tot4 = NNODES * 16;
    if (i >= tot4) return;
    float4 a = e0[i], b = e1[i], c = e2[i], d = e3[i];
    float4 m;
    m.x = (a.x + b.x + c.x + d.x) * 0.25f;
    m.y = (a.y + b.y + c.y + d.y) * 0.25f;
    m.z = (a.z + b.z + c.z + d.z) * 0.25f;
    m.w = (a.w + b.w + c.w + d.w) * 0.25f;
    const int nu4 = NUSERS * 16;
    if (i < nu4) users[i] = m;
    else         items[i - nu4] = m;
}

extern "C" void kernel_launch(void* const* d_in, const int* in_sizes, int n_in,
                              void* d_out, int out_size, void* d_ws, size_t ws_size,
                              hipStream_t stream) {
    const float* user_emb = (const float*)d_in[0];
    const float* item_emb = (const float*)d_in[1];
    const int*   adj_row  = (const int*)d_in[2];
    const int*   adj_col  = (const int*)d_in[3];
    const float* adj_val  = (const float*)d_in[4];

    float* out   = (float*)d_out;
    float* users = out;
    float* items = out + (size_t)NUSERS * DIM;
    float* e0    = out + (size_t)NNODES * DIM;
    float* e1    = e0 + (size_t)NNODES * DIM;
    float* e2    = e1 + (size_t)NNODES * DIM;
    float* e3    = e2 + (size_t)NNODES * DIM;

    // fp8 gather tables (19.2 MB each) ping-pong inside the users+items
    // region (76.8 MB); finalize overwrites them at the end.
    unsigned* tA = (unsigned*)out;                       // t0, t2
    unsigned* tB = tA + (size_t)NNODES * 16;             // t1

    const int tot4  = NNODES * 16;
    const int cblk  = 256;
    const int cgrid = (tot4 + cblk - 1) / cblk;

    // workspace (~66 MB)
    char* ws = (char*)d_ws;
    size_t off = 0;
    auto alloc = [&](size_t bytes) {
        char* p = ws + off;
        off += (bytes + 255) & ~(size_t)255;
        return p;
    };
    int*            gcurs  = (int*)            alloc((size_t)K1 * GCS * sizeof(int));
    int*            rstart = (int*)            alloc((size_t)NNODES * sizeof(int));
    unsigned*       keys   = (unsigned*)       alloc((size_t)K1 * CAP1 * sizeof(unsigned));
    unsigned short* vals   = (unsigned short*) alloc((size_t)K1 * CAP1 * sizeof(unsigned short));
    bool have_ws = (off <= ws_size);

    concat_kernel<<<cgrid, cblk, 0, stream>>>(
        (const float4*)user_emb, (const float4*)item_emb, (float4*)e0, tA);

    if (have_ws) {
        zero_kernel<<<(K1 * GCS + 255) / 256, 256, 0, stream>>>(gcurs, K1 * GCS);
        part_kernel<<<PNBLK, PTHREADS, 0, stream>>>(adj_row, adj_col, adj_val,
                                                    gcurs, keys, vals);
        bsort_kernel<<<K1, 512, 0, stream>>>(gcurs, keys, vals, rstart);

        const int sgrid = (NNODES * 16 + 255) / 256;   // 18750
        spmm_kernel<true,  4><<<sgrid, 256, 0, stream>>>(rstart, gcurs, keys, vals,
                                                         tA, (float4*)e1, tB);
        spmm_kernel<true,  8><<<sgrid, 256, 0, stream>>>(rstart, gcurs, keys, vals,
                                                         tB, (float4*)e2, tA);
        spmm_kernel<false, 12><<<sgrid, 256, 0, stream>>>(rstart, gcurs, keys, vals,
                                                          tA, (float4*)e3, nullptr);
    } else {
        hipMemsetAsync(e1, 0, (size_t)3 * NNODES * DIM * sizeof(float), stream);
        const long long st = (long long)NEDGES * 16;
        const int sgrid = (int)((st + 255) / 256);
        spmm_atomic_kernel<<<sgrid, 256, 0, stream>>>(adj_row, adj_col, adj_val, e0, e1);
        spmm_atomic_kernel<<<sgrid, 256, 0, stream>>>(adj_row, adj_col, adj_val, e1, e2);
        spmm_atomic_kernel<<<sgrid, 256, 0, stream>>>(adj_row, adj_col, adj_val, e2, e3);
    }

    finalize_kernel<<<cgrid, cblk, 0, stream>>>(
        (const float4*)e0, (const float4*)e1, (const float4*)e2, (const float4*)e3,
        (float4*)users, (float4*)items);
}